// Round 5
// baseline (348.745 us; speedup 1.0000x reference)
//
#include <hip/hip_runtime.h>
#include <hip/hip_bf16.h>
#include <stdint.h>

#define B_ROWS 131072
#define DDIM 256
#define GATE_BLOCKS 4096          // B_ROWS / 32 (8 threads/row, 128B-coalesced)
#define PREPACK_BLOCKS 56         // 7 matrices x 8 s-slabs
#define MLP_BLOCKS 2051           // sum_e ceil(cnt_e/64) <= 2048 + 3

typedef short bf16x8 __attribute__((ext_vector_type(8)));
typedef float f32x4 __attribute__((ext_vector_type(4)));

__device__ __forceinline__ unsigned short f32_to_bf16_rne(float f) {
    union { float f; uint32_t u; } v; v.f = f;
    uint32_t u = v.u;
    u += 0x7fffu + ((u >> 16) & 1u);
    return (unsigned short)(u >> 16);
}

// pack two f32 -> one dword of 2 bf16 (RNE), low = a, high = b
__device__ __forceinline__ uint32_t cvt_pk_bf16(float a, float b) {
    uint32_t r;
    asm("v_cvt_pk_bf16_f32 %0, %1, %2" : "=v"(r) : "v"(a), "v"(b));
    return r;
}

// ---------------------------------------------------------------------------
// Fused kernel A: blocks [0,4096) = gate (32 rows/block, 8 thr/row so each
// row-iteration reads one contiguous 128B line), blocks [4096,4152) =
// weight prepack into MFMA B-frag order (bf16).
// B-frag layout: packed[s][t][lane][j] = W[32s + 8*(lane>>4) + j][16t + (lane&15)]
// ---------------------------------------------------------------------------
__global__ __launch_bounds__(256) void gate_prepack_kernel(
    const float* __restrict__ x, const float* __restrict__ Wg,
    const float* __restrict__ bg, const float* __restrict__ Wl,
    const float* __restrict__ Wm, const float* __restrict__ Wr,
    int* __restrict__ counts, int* __restrict__ perm,
    unsigned short* __restrict__ wpack)
{
    __shared__ float smemf[4160];          // 16640 B, shared by both roles
    int t = threadIdx.x;

    if (blockIdx.x >= GATE_BLOCKS) {
        // ----- prepack: one (matrix m, s-slab) per block -----
        int bid = blockIdx.x - GATE_BLOCKS;
        int m = bid >> 3, s = bid & 7;
        const float* src = (m < 4) ? (Wl + m * 65536)
                         : (m < 6) ? (Wm + (m - 4) * 65536)
                                   : Wr;
        unsigned short* lds = (unsigned short*)smemf;   // 8192 ushorts = 1024 uint4
        #pragma unroll
        for (int i = 0; i < 8; i++) {
            int v = i * 256 + t;            // float4 id within 32x256 slab
            int kp = v >> 6;                // 0..31 (k - 32s)
            int n0 = (v & 63) * 4;
            float4 w = *(const float4*)(src + (32 * s + kp) * 256 + n0);
            #pragma unroll
            for (int c = 0; c < 4; c++) {
                int n = n0 + c;
                float val = (c == 0) ? w.x : (c == 1) ? w.y : (c == 2) ? w.z : w.w;
                int o = (n >> 4) * 512 + ((n & 15) + 16 * (kp >> 3)) * 8 + (kp & 7);
                lds[o] = f32_to_bf16_rne(val);
            }
        }
        __syncthreads();
        uint4* outv = (uint4*)(wpack + (m * 8 + s) * 8192);
        const uint4* ldsv = (const uint4*)lds;
        #pragma unroll
        for (int q = 0; q < 4; q++)
            outv[q * 256 + t] = ldsv[q * 256 + t];
        return;
    }

    // ----- gate: 32 rows per block, 8 threads per row (fp64-exact argmax) -----
    // Per iteration i, a row's 8 subs read 8 x float4 = one contiguous 128B
    // line (vs 64B with 4 subs) -> full-line HBM transactions on cold x.
    float* wgl = smemf;                    // Wg[k][e] flat, 1024 floats
    int* hcount = (int*)(smemf + 1024);
    int* hbase  = (int*)(smemf + 1028);

    ((float4*)wgl)[t] = ((const float4*)Wg)[t];
    if (t < 4) hcount[t] = 0;
    __syncthreads();

    int lrow = t >> 3, sub = t & 7;
    int row = blockIdx.x * 32 + lrow;
    const float* xr = x + (long)row * DDIM;

    double a0 = 0.0, a1 = 0.0, a2 = 0.0, a3 = 0.0;
    #pragma unroll
    for (int i = 0; i < 8; i++) {
        int k0 = i * 32 + sub * 4;
        float4 v = *(const float4*)(xr + k0);
        #pragma unroll
        for (int kk = 0; kk < 4; kk++) {
            float xv = (kk == 0) ? v.x : (kk == 1) ? v.y : (kk == 2) ? v.z : v.w;
            float4 w = *(const float4*)(wgl + (k0 + kk) * 4);   // ds_read_b128
            a0 += (double)xv * (double)w.x;
            a1 += (double)xv * (double)w.y;
            a2 += (double)xv * (double)w.z;
            a3 += (double)xv * (double)w.w;
        }
    }
    // reduce across the row's 8 lanes (aligned 8-lane group within the wave)
    a0 += __shfl_xor(a0, 1); a0 += __shfl_xor(a0, 2); a0 += __shfl_xor(a0, 4);
    a1 += __shfl_xor(a1, 1); a1 += __shfl_xor(a1, 2); a1 += __shfl_xor(a1, 4);
    a2 += __shfl_xor(a2, 1); a2 += __shfl_xor(a2, 2); a2 += __shfl_xor(a2, 4);
    a3 += __shfl_xor(a3, 1); a3 += __shfl_xor(a3, 2); a3 += __shfl_xor(a3, 4);

    int myidx = 0, mylpos = 0;
    if (sub == 0) {
        double l0 = a0 + (double)bg[0];
        double l1 = a1 + (double)bg[1];
        double l2 = a2 + (double)bg[2];
        double l3 = a3 + (double)bg[3];
        double best = l0; myidx = 0;
        if (l1 > best) { best = l1; myidx = 1; }   // strict > = first-max tiebreak
        if (l2 > best) { best = l2; myidx = 2; }
        if (l3 > best) { best = l3; myidx = 3; }
        mylpos = atomicAdd(&hcount[myidx], 1);
    }
    __syncthreads();
    if (t < 4) hbase[t] = atomicAdd(&counts[t], hcount[t]);
    __syncthreads();
    if (sub == 0) perm[myidx * B_ROWS + hbase[myidx] + mylpos] = row;
}

// ---------------------------------------------------------------------------
// Kernel B (unchanged from round 4): fused 3-layer MLP. Block = 64 rows,
// 512 thr (8 waves). SWAPPED-OPERAND MFMA: D = mfma(Wfrag, Xfrag) = (X W)^T,
// so each lane holds 4 CONSECUTIVE output columns of ONE sample row:
//   acc[ot][st][r] = H[16 st + (l&15)][16 (2wv+ot) + 4 (l>>4) + r]
// -> epilogue = 2x cvt_pk + one ds_write_b64 per tile, bias = float4 load,
//    final store = float4 (16B write granules).
// Wave wv owns outcol-tiles {2wv, 2wv+1} x all 4 sample-tiles: acc = 32 regs.
// Grid exact: (e,tile) from counts[] prefix, 2051 blocks. LDS 32.5 KB.
// apack layout [s:8][st:4][lane:64][j:8] bf16, conflict-free ds_read_b128.
// ---------------------------------------------------------------------------
__global__ __launch_bounds__(512, 6) void mlp_kernel(
    const float* __restrict__ x, const unsigned short* __restrict__ wpack,
    const float* __restrict__ b_leaf, const float* __restrict__ b_mid,
    const float* __restrict__ b_root, const int* __restrict__ counts,
    const int* __restrict__ perm, float* __restrict__ out)
{
    __shared__ unsigned short apack[16384];   // 32 KB
    __shared__ int rowsLds[64];

    // exact work mapping from counts prefix (uniform per block, scalar path)
    int c0 = counts[0], c1 = counts[1], c2 = counts[2], c3 = counts[3];
    int t0 = (c0 + 63) >> 6;
    int t01 = t0 + ((c1 + 63) >> 6);
    int t012 = t01 + ((c2 + 63) >> 6);
    int tall = t012 + ((c3 + 63) >> 6);
    int bid = blockIdx.x;
    if (bid >= tall) return;
    int e, tile, cnt;
    if (bid < t0)        { e = 0; tile = bid;        cnt = c0; }
    else if (bid < t01)  { e = 1; tile = bid - t0;   cnt = c1; }
    else if (bid < t012) { e = 2; tile = bid - t01;  cnt = c2; }
    else                 { e = 3; tile = bid - t012; cnt = c3; }
    int base = tile * 64;

    int t = threadIdx.x;
    if (t < 64) {
        int src = base + t;
        rowsLds[t] = perm[e * B_ROWS + (src < cnt ? src : base)];
    }
    __syncthreads();

    // gather X -> LDS packed B-frags (8 threads per row, cvt_pk converts)
    {
        int r = t >> 3, sub = t & 7;
        const float* xr = x + (long)rowsLds[r] * DDIM;
        int st = r >> 4, rl = r & 15;
        #pragma unroll
        for (int i = 0; i < 8; i++) {
            int k0 = i * 32 + sub * 4;
            float4 v = *(const float4*)(xr + k0);
            int s = k0 >> 5;                   // = i
            int fl = rl + 16 * ((k0 >> 3) & 3);
            uint2 u;
            u.x = cvt_pk_bf16(v.x, v.y);
            u.y = cvt_pk_bf16(v.z, v.w);
            *(uint2*)&apack[((s * 4 + st) * 64 + fl) * 8 + (k0 & 7)] = u;
        }
    }
    __syncthreads();

    int wv = t >> 6, l = t & 63;
    int q = l >> 4;                 // reg-quad index: outcol sub-offset 4q
    f32x4 acc[2][4];

    auto run_level = [&](const unsigned short* wp) {
        f32x4 z = {0.f, 0.f, 0.f, 0.f};
        #pragma unroll
        for (int ot = 0; ot < 2; ot++)
            #pragma unroll
            for (int st = 0; st < 4; st++) acc[ot][st] = z;

        const bf16x8* wpv = (const bf16x8*)wp;
        #pragma unroll
        for (int s = 0; s < 8; s++) {
            bf16x8 wa[2];
            #pragma unroll
            for (int ot = 0; ot < 2; ot++)
                wa[ot] = wpv[(s * 16 + 2 * wv + ot) * 64 + l];   // W^T as A-operand
            const bf16x8* ap = (const bf16x8*)(apack + s * 4 * 64 * 8);
            #pragma unroll
            for (int st = 0; st < 4; st++) {
                bf16x8 xb = ap[st * 64 + l];                      // X^T as B-operand
                #pragma unroll
                for (int ot = 0; ot < 2; ot++)
                    acc[ot][st] = __builtin_amdgcn_mfma_f32_16x16x32_bf16(
                        wa[ot], xb, acc[ot][st], 0, 0, 0);
            }
        }
    };

    // write relu(acc + bias) back into apack as next level's B-frags
    auto epilogue_lds = [&](const float* bias_g) {
        #pragma unroll
        for (int ot = 0; ot < 2; ot++) {
            int kb = (2 * wv + ot) * 16 + 4 * q;    // 4 consecutive outcols
            float4 bv = *(const float4*)(bias_g + kb);
            int s2 = kb >> 5;
            int hq = (kb >> 3) & 3;
            int jb = kb & 7;                         // 0 or 4
            #pragma unroll
            for (int st = 0; st < 4; st++) {
                float v0 = fmaxf(acc[ot][st][0] + bv.x, 0.f);
                float v1 = fmaxf(acc[ot][st][1] + bv.y, 0.f);
                float v2 = fmaxf(acc[ot][st][2] + bv.z, 0.f);
                float v3 = fmaxf(acc[ot][st][3] + bv.w, 0.f);
                uint2 u;
                u.x = cvt_pk_bf16(v0, v1);
                u.y = cvt_pk_bf16(v2, v3);
                *(uint2*)&apack[((s2 * 4 + st) * 64 + (l & 15) + 16 * hq) * 8 + jb] = u;
            }
        }
    };

    // level 1: leaf expert e
    run_level(wpack + e * 65536);
    __syncthreads();
    epilogue_lds(b_leaf + e * 256);
    __syncthreads();

    // level 2: mid expert e>>1
    run_level(wpack + (4 + (e >> 1)) * 65536);
    __syncthreads();
    epilogue_lds(b_mid + (e >> 1) * 256);
    __syncthreads();

    // level 3: root, float4 scatter-store
    run_level(wpack + 6 * 65536);
    #pragma unroll
    for (int ot = 0; ot < 2; ot++) {
        int kb = (2 * wv + ot) * 16 + 4 * q;
        float4 bv = *(const float4*)(b_root + kb);
        #pragma unroll
        for (int st = 0; st < 4; st++) {
            int ls = st * 16 + (l & 15);
            if (base + ls < cnt) {
                float4 o4;
                o4.x = fmaxf(acc[ot][st][0] + bv.x, 0.f);
                o4.y = fmaxf(acc[ot][st][1] + bv.y, 0.f);
                o4.z = fmaxf(acc[ot][st][2] + bv.z, 0.f);
                o4.w = fmaxf(acc[ot][st][3] + bv.w, 0.f);
                *(float4*)(out + (long)rowsLds[ls] * DDIM + kb) = o4;
            }
        }
    }
}

extern "C" void kernel_launch(void* const* d_in, const int* in_sizes, int n_in,
                              void* d_out, int out_size, void* d_ws, size_t ws_size,
                              hipStream_t stream) {
    const float* x      = (const float*)d_in[0];
    const float* Wg     = (const float*)d_in[1];
    const float* bg     = (const float*)d_in[2];
    const float* W_leaf = (const float*)d_in[3];
    const float* b_leaf = (const float*)d_in[4];
    const float* W_mid  = (const float*)d_in[5];
    const float* b_mid  = (const float*)d_in[6];
    const float* W_root = (const float*)d_in[7];
    const float* b_root = (const float*)d_in[8];
    float* out = (float*)d_out;

    char* ws = (char*)d_ws;
    int* counts = (int*)ws;                                    // 16 B
    int* perm = (int*)(ws + 256);                              // 2 MB
    unsigned short* wpack = (unsigned short*)(ws + (4 << 20)); // 896 KB

    hipMemsetAsync(counts, 0, 16, stream);
    gate_prepack_kernel<<<GATE_BLOCKS + PREPACK_BLOCKS, 256, 0, stream>>>(
        x, Wg, bg, W_leaf, W_mid, W_root, counts, perm, wpack);
    mlp_kernel<<<MLP_BLOCKS, 512, 0, stream>>>(
        x, wpack, b_leaf, b_mid, b_root, counts, perm, out);
}

// Round 6
// 332.086 us; speedup vs baseline: 1.0502x; 1.0502x over previous
//
#include <hip/hip_runtime.h>
#include <hip/hip_bf16.h>
#include <stdint.h>

#define B_ROWS 131072
#define DDIM 256
#define GATE_BLOCKS 2048          // B_ROWS / 64
#define PREPACK_BLOCKS 56         // 7 matrices x 8 s-slabs
#define MLP_BLOCKS 2051           // sum_e ceil(cnt_e/64) <= 2048 + 3

typedef short bf16x8 __attribute__((ext_vector_type(8)));
typedef float f32x4 __attribute__((ext_vector_type(4)));

__device__ __forceinline__ unsigned short f32_to_bf16_rne(float f) {
    union { float f; uint32_t u; } v; v.f = f;
    uint32_t u = v.u;
    u += 0x7fffu + ((u >> 16) & 1u);
    return (unsigned short)(u >> 16);
}

// pack two f32 -> one dword of 2 bf16 (RNE), low = a, high = b
__device__ __forceinline__ uint32_t cvt_pk_bf16(float a, float b) {
    uint32_t r;
    asm("v_cvt_pk_bf16_f32 %0, %1, %2" : "=v"(r) : "v"(a), "v"(b));
    return r;
}

// ---------------------------------------------------------------------------
// Fused kernel A (reverted to round-4 form, known-good 334.8us):
// blocks [0,2048) = gate (64 rows/block, 4 thr/row, fp64-exact argmax),
// blocks [2048,2104) = weight prepack into MFMA B-frag order (bf16).
// B-frag layout: packed[s][t][lane][j] = W[32s + 8*(lane>>4) + j][16t + (lane&15)]
// ---------------------------------------------------------------------------
__global__ __launch_bounds__(256) void gate_prepack_kernel(
    const float* __restrict__ x, const float* __restrict__ Wg,
    const float* __restrict__ bg, const float* __restrict__ Wl,
    const float* __restrict__ Wm, const float* __restrict__ Wr,
    int* __restrict__ counts, int* __restrict__ perm,
    unsigned short* __restrict__ wpack)
{
    __shared__ float smemf[4160];          // 16640 B, shared by both roles
    int t = threadIdx.x;

    if (blockIdx.x >= GATE_BLOCKS) {
        // ----- prepack: one (matrix m, s-slab) per block -----
        int bid = blockIdx.x - GATE_BLOCKS;
        int m = bid >> 3, s = bid & 7;
        const float* src = (m < 4) ? (Wl + m * 65536)
                         : (m < 6) ? (Wm + (m - 4) * 65536)
                                   : Wr;
        unsigned short* lds = (unsigned short*)smemf;   // 8192 ushorts = 1024 uint4
        #pragma unroll
        for (int i = 0; i < 8; i++) {
            int v = i * 256 + t;            // float4 id within 32x256 slab
            int kp = v >> 6;                // 0..31 (k - 32s)
            int n0 = (v & 63) * 4;
            float4 w = *(const float4*)(src + (32 * s + kp) * 256 + n0);
            #pragma unroll
            for (int c = 0; c < 4; c++) {
                int n = n0 + c;
                float val = (c == 0) ? w.x : (c == 1) ? w.y : (c == 2) ? w.z : w.w;
                int o = (n >> 4) * 512 + ((n & 15) + 16 * (kp >> 3)) * 8 + (kp & 7);
                lds[o] = f32_to_bf16_rne(val);
            }
        }
        __syncthreads();
        uint4* outv = (uint4*)(wpack + (m * 8 + s) * 8192);
        const uint4* ldsv = (const uint4*)lds;
        #pragma unroll
        for (int q = 0; q < 4; q++)
            outv[q * 256 + t] = ldsv[q * 256 + t];
        return;
    }

    // ----- gate: 64 rows per block, 4 threads per row (fp64-exact argmax) -----
    float* wgl = smemf;                    // Wg[k][e] flat, 1024 floats
    int* hcount = (int*)(smemf + 1024);
    int* hbase  = (int*)(smemf + 1028);

    ((float4*)wgl)[t] = ((const float4*)Wg)[t];
    if (t < 4) hcount[t] = 0;
    __syncthreads();

    int lrow = t >> 2, sub = t & 3;
    int row = blockIdx.x * 64 + lrow;
    const float* xr = x + (long)row * DDIM;

    double a0 = 0.0, a1 = 0.0, a2 = 0.0, a3 = 0.0;
    #pragma unroll
    for (int i = 0; i < 16; i++) {
        int k0 = i * 16 + sub * 4;
        float4 v = *(const float4*)(xr + k0);
        #pragma unroll
        for (int kk = 0; kk < 4; kk++) {
            float xv = (kk == 0) ? v.x : (kk == 1) ? v.y : (kk == 2) ? v.z : v.w;
            float4 w = *(const float4*)(wgl + (k0 + kk) * 4);   // ds_read_b128
            a0 += (double)xv * (double)w.x;
            a1 += (double)xv * (double)w.y;
            a2 += (double)xv * (double)w.z;
            a3 += (double)xv * (double)w.w;
        }
    }
    a0 += __shfl_xor(a0, 1); a0 += __shfl_xor(a0, 2);
    a1 += __shfl_xor(a1, 1); a1 += __shfl_xor(a1, 2);
    a2 += __shfl_xor(a2, 1); a2 += __shfl_xor(a2, 2);
    a3 += __shfl_xor(a3, 1); a3 += __shfl_xor(a3, 2);

    int myidx = 0, mylpos = 0;
    if (sub == 0) {
        double l0 = a0 + (double)bg[0];
        double l1 = a1 + (double)bg[1];
        double l2 = a2 + (double)bg[2];
        double l3 = a3 + (double)bg[3];
        double best = l0; myidx = 0;
        if (l1 > best) { best = l1; myidx = 1; }   // strict > = first-max tiebreak
        if (l2 > best) { best = l2; myidx = 2; }
        if (l3 > best) { best = l3; myidx = 3; }
        mylpos = atomicAdd(&hcount[myidx], 1);
    }
    __syncthreads();
    if (t < 4) hbase[t] = atomicAdd(&counts[t], hcount[t]);
    __syncthreads();
    if (sub == 0) perm[myidx * B_ROWS + hbase[myidx] + mylpos] = row;
}

// ---------------------------------------------------------------------------
// Kernel B: fused 3-layer MLP. Block = 64 rows, 512 thr (8 waves).
// SWAPPED-OPERAND MFMA: D = mfma(Wfrag, Xfrag) = (X W)^T, so each lane holds
// 4 CONSECUTIVE output columns of ONE sample row:
//   acc[ot][st][r] = H[16 st + (l&15)][16 (2wv+ot) + 4 (l>>4) + r]
// W-frags read directly from global (L2-resident wpack); X-frags from LDS.
// NEW vs round 4: W-frag loads software-pipelined one s-step ahead (named
// rotation regs -> forces L2 latency under the MFMA cluster; +8 VGPR only),
// and s_setprio(1) around each MFMA cluster (blocks on a CU sit at
// different phases -> scheduler can favor MFMA-issuing waves).
// Grid exact: (e,tile) from counts[] prefix, 2051 blocks. LDS 32.5 KB.
// apack layout [s:8][st:4][lane:64][j:8] bf16, conflict-free ds_read_b128.
// ---------------------------------------------------------------------------
__global__ __launch_bounds__(512, 6) void mlp_kernel(
    const float* __restrict__ x, const unsigned short* __restrict__ wpack,
    const float* __restrict__ b_leaf, const float* __restrict__ b_mid,
    const float* __restrict__ b_root, const int* __restrict__ counts,
    const int* __restrict__ perm, float* __restrict__ out)
{
    __shared__ unsigned short apack[16384];   // 32 KB
    __shared__ int rowsLds[64];

    // exact work mapping from counts prefix (uniform per block, scalar path)
    int c0 = counts[0], c1 = counts[1], c2 = counts[2], c3 = counts[3];
    int t0 = (c0 + 63) >> 6;
    int t01 = t0 + ((c1 + 63) >> 6);
    int t012 = t01 + ((c2 + 63) >> 6);
    int tall = t012 + ((c3 + 63) >> 6);
    int bid = blockIdx.x;
    if (bid >= tall) return;
    int e, tile, cnt;
    if (bid < t0)        { e = 0; tile = bid;        cnt = c0; }
    else if (bid < t01)  { e = 1; tile = bid - t0;   cnt = c1; }
    else if (bid < t012) { e = 2; tile = bid - t01;  cnt = c2; }
    else                 { e = 3; tile = bid - t012; cnt = c3; }
    int base = tile * 64;

    int t = threadIdx.x;
    if (t < 64) {
        int src = base + t;
        rowsLds[t] = perm[e * B_ROWS + (src < cnt ? src : base)];
    }
    __syncthreads();

    // gather X -> LDS packed B-frags (8 threads per row, cvt_pk converts)
    {
        int r = t >> 3, sub = t & 7;
        const float* xr = x + (long)rowsLds[r] * DDIM;
        int st = r >> 4, rl = r & 15;
        #pragma unroll
        for (int i = 0; i < 8; i++) {
            int k0 = i * 32 + sub * 4;
            float4 v = *(const float4*)(xr + k0);
            int s = k0 >> 5;                   // = i
            int fl = rl + 16 * ((k0 >> 3) & 3);
            uint2 u;
            u.x = cvt_pk_bf16(v.x, v.y);
            u.y = cvt_pk_bf16(v.z, v.w);
            *(uint2*)&apack[((s * 4 + st) * 64 + fl) * 8 + (k0 & 7)] = u;
        }
    }
    __syncthreads();

    int wv = t >> 6, l = t & 63;
    int q = l >> 4;                 // reg-quad index: outcol sub-offset 4q
    f32x4 acc[2][4];

    auto run_level = [&](const unsigned short* wp) {
        f32x4 z = {0.f, 0.f, 0.f, 0.f};
        #pragma unroll
        for (int ot = 0; ot < 2; ot++)
            #pragma unroll
            for (int st = 0; st < 4; st++) acc[ot][st] = z;

        const bf16x8* wpv = (const bf16x8*)wp;
        const bf16x8* ap = (const bf16x8*)apack;
        int wbase = (2 * wv) * 64 + l;        // frag idx for (s=0, ot=0)

        // prologue: preload s=0 W-frags
        bf16x8 wa0 = wpv[wbase];
        bf16x8 wa1 = wpv[wbase + 64];

        #pragma unroll
        for (int s = 0; s < 8; s++) {
            bf16x8 nwa0, nwa1;
            if (s < 7) {                       // issue s+1 W loads EARLY
                nwa0 = wpv[(s + 1) * 1024 + wbase];
                nwa1 = wpv[(s + 1) * 1024 + wbase + 64];
            }
            const bf16x8* aps = ap + s * 256;
            __builtin_amdgcn_s_setprio(1);
            #pragma unroll
            for (int st = 0; st < 4; st++) {
                bf16x8 xb = aps[st * 64 + l];                 // X^T as B-operand
                acc[0][st] = __builtin_amdgcn_mfma_f32_16x16x32_bf16(
                    wa0, xb, acc[0][st], 0, 0, 0);
                acc[1][st] = __builtin_amdgcn_mfma_f32_16x16x32_bf16(
                    wa1, xb, acc[1][st], 0, 0, 0);
            }
            __builtin_amdgcn_s_setprio(0);
            if (s < 7) { wa0 = nwa0; wa1 = nwa1; }
        }
    };

    // write relu(acc + bias) back into apack as next level's B-frags
    auto epilogue_lds = [&](const float* bias_g) {
        #pragma unroll
        for (int ot = 0; ot < 2; ot++) {
            int kb = (2 * wv + ot) * 16 + 4 * q;    // 4 consecutive outcols
            float4 bv = *(const float4*)(bias_g + kb);
            int s2 = kb >> 5;
            int hq = (kb >> 3) & 3;
            int jb = kb & 7;                         // 0 or 4
            #pragma unroll
            for (int st = 0; st < 4; st++) {
                float v0 = fmaxf(acc[ot][st][0] + bv.x, 0.f);
                float v1 = fmaxf(acc[ot][st][1] + bv.y, 0.f);
                float v2 = fmaxf(acc[ot][st][2] + bv.z, 0.f);
                float v3 = fmaxf(acc[ot][st][3] + bv.w, 0.f);
                uint2 u;
                u.x = cvt_pk_bf16(v0, v1);
                u.y = cvt_pk_bf16(v2, v3);
                *(uint2*)&apack[((s2 * 4 + st) * 64 + (l & 15) + 16 * hq) * 8 + jb] = u;
            }
        }
    };

    // level 1: leaf expert e
    run_level(wpack + e * 65536);
    __syncthreads();
    epilogue_lds(b_leaf + e * 256);
    __syncthreads();

    // level 2: mid expert e>>1
    run_level(wpack + (4 + (e >> 1)) * 65536);
    __syncthreads();
    epilogue_lds(b_mid + (e >> 1) * 256);
    __syncthreads();

    // level 3: root, float4 scatter-store
    run_level(wpack + 6 * 65536);
    #pragma unroll
    for (int ot = 0; ot < 2; ot++) {
        int kb = (2 * wv + ot) * 16 + 4 * q;
        float4 bv = *(const float4*)(b_root + kb);
        #pragma unroll
        for (int st = 0; st < 4; st++) {
            int ls = st * 16 + (l & 15);
            if (base + ls < cnt) {
                float4 o4;
                o4.x = fmaxf(acc[ot][st][0] + bv.x, 0.f);
                o4.y = fmaxf(acc[ot][st][1] + bv.y, 0.f);
                o4.z = fmaxf(acc[ot][st][2] + bv.z, 0.f);
                o4.w = fmaxf(acc[ot][st][3] + bv.w, 0.f);
                *(float4*)(out + (long)rowsLds[ls] * DDIM + kb) = o4;
            }
        }
    }
}

extern "C" void kernel_launch(void* const* d_in, const int* in_sizes, int n_in,
                              void* d_out, int out_size, void* d_ws, size_t ws_size,
                              hipStream_t stream) {
    const float* x      = (const float*)d_in[0];
    const float* Wg     = (const float*)d_in[1];
    const float* bg     = (const float*)d_in[2];
    const float* W_leaf = (const float*)d_in[3];
    const float* b_leaf = (const float*)d_in[4];
    const float* W_mid  = (const float*)d_in[5];
    const float* b_mid  = (const float*)d_in[6];
    const float* W_root = (const float*)d_in[7];
    const float* b_root = (const float*)d_in[8];
    float* out = (float*)d_out;

    char* ws = (char*)d_ws;
    int* counts = (int*)ws;                                    // 16 B
    int* perm = (int*)(ws + 256);                              // 2 MB
    unsigned short* wpack = (unsigned short*)(ws + (4 << 20)); // 896 KB

    hipMemsetAsync(counts, 0, 16, stream);
    gate_prepack_kernel<<<GATE_BLOCKS + PREPACK_BLOCKS, 256, 0, stream>>>(
        x, Wg, bg, W_leaf, W_mid, W_root, counts, perm, wpack);
    mlp_kernel<<<MLP_BLOCKS, 512, 0, stream>>>(
        x, wpack, b_leaf, b_mid, b_root, counts, perm, out);
}